// Round 7
// baseline (510.997 us; speedup 1.0000x reference)
//
#include <hip/hip_runtime.h>
#include <math.h>

namespace {

typedef short s16;
typedef short s16x8 __attribute__((ext_vector_type(8)));
typedef float f32x4 __attribute__((ext_vector_type(4)));

constexpr int B   = 2;
constexpr int S   = 2048;
constexpr int H   = 2048;
constexpr int NH  = 16;
constexpr int NKV = 4;
constexpr int HD  = 128;
constexpr int WIN = 1024;
constexpr int M   = B * S;       // 4096

// ---- fp32 -> bf16 (RNE) as raw short ----
__device__ inline s16 f2bs(float x) {
    unsigned u = __float_as_uint(x);
    u += 0x7fffu + ((u >> 16) & 1u);
    return (s16)(u >> 16);
}
// ---- bf16 bits -> fp32 ----
__device__ inline float bs2f(s16 v) {
    return __uint_as_float(((unsigned)(unsigned short)v) << 16);
}

__device__ inline void gload_lds16(const void* g, void* l) {
    __builtin_amdgcn_global_load_lds(
        (const __attribute__((address_space(1))) void*)g,
        (__attribute__((address_space(3))) void*)l, 16, 0, 0);
}

// ---------- fp32 -> bf16 cast, 8 elems/thread ----------
__global__ __launch_bounds__(256) void cast_kernel(const float* __restrict__ X,
                                                   s16* __restrict__ Y, int n8) {
    int i = blockIdx.x * 256 + threadIdx.x;
    if (i >= n8) return;
    const float4* p = (const float4*)X + (size_t)i * 2;
    float4 a = p[0], b = p[1];
    s16x8 v;
    v[0] = f2bs(a.x); v[1] = f2bs(a.y); v[2] = f2bs(a.z); v[3] = f2bs(a.w);
    v[4] = f2bs(b.x); v[5] = f2bs(b.y); v[6] = f2bs(b.z); v[7] = f2bs(b.w);
    *(s16x8*)(Y + (size_t)i * 8) = v;
}

// ---------- W[K][N] fp32 -> WT[N][K] bf16 ----------
__global__ __launch_bounds__(256) void transpose_cast(const float* __restrict__ W,
                                                      s16* __restrict__ WT,
                                                      int K, int N) {
    __shared__ float tile[64][65];
    int c = threadIdx.x & 63, r4 = threadIdx.x >> 6;
    int nb = blockIdx.x * 64, kb = blockIdx.y * 64;
    #pragma unroll
    for (int i = 0; i < 16; ++i) {
        int r = r4 + i * 4;
        tile[r][c] = W[(size_t)(kb + r) * N + nb + c];
    }
    __syncthreads();
    #pragma unroll
    for (int i = 0; i < 16; ++i) {
        int r = r4 + i * 4;
        WT[(size_t)(nb + r) * K + kb + c] = f2bs(tile[c][r]);
    }
}

// ---------- bf16 MFMA GEMM: C[M,N] = A[M,K] @ BT[N,K]^T ----------
// 128x128 tile, BK=32, 4 waves (2x2), 4x4 16x16x32 frags per wave.
// LDS XOR-swizzled at 16B granularity (superrow=128B, slot'=slot^(sr&7)).
template <bool BF16OUT>
__global__ __launch_bounds__(256) void gemm_bf16(const s16* __restrict__ A,
                                                 const s16* __restrict__ BT,
                                                 void* __restrict__ Cv,
                                                 int Ndim, int Kdim) {
    __shared__ __align__(16) s16 As[128 * 32];
    __shared__ __align__(16) s16 Bs[128 * 32];

    const int t    = threadIdx.x;
    const int lane = t & 63;
    const int wid  = t >> 6;
    const int wr   = wid >> 1;
    const int wc   = wid & 1;
    const int rowBase = blockIdx.y * 128;
    const int colBase = blockIdx.x * 128;

    const s16* Ab = A  + (size_t)rowBase * Kdim;
    const s16* Bb = BT + (size_t)colBase * Kdim;

    f32x4 acc[4][4];
    #pragma unroll
    for (int m = 0; m < 4; ++m)
        #pragma unroll
        for (int n = 0; n < 4; ++n)
            acc[m][n] = (f32x4)0.f;

    for (int k0 = 0; k0 < Kdim; k0 += 32) {
        #pragma unroll
        for (int i = 0; i < 2; ++i) {
            int lc = i * 256 + t;             // 16B chunk 0..511
            int sr = lc >> 3;                 // 128B superrow
            int cc = (lc & 7) ^ (sr & 7);     // source chunk in superrow
            int r  = (sr << 1) | (cc >> 2);
            int kg = cc & 3;
            const s16* ga = Ab + (size_t)r * Kdim + k0 + kg * 8;
            const s16* gb = Bb + (size_t)r * Kdim + k0 + kg * 8;
            char* la = (char*)As + i * 4096 + wid * 1024;
            char* lb = (char*)Bs + i * 4096 + wid * 1024;
            gload_lds16(ga, la);
            gload_lds16(gb, lb);
        }
        __syncthreads();

        s16x8 af[4], bfr[4];
        #pragma unroll
        for (int m = 0; m < 4; ++m) {
            int r  = wr * 64 + m * 16 + (lane & 15);
            int sr = r >> 1;
            int c  = ((r & 1) << 2) | (lane >> 4);
            int cs = c ^ (sr & 7);
            af[m] = *(const s16x8*)(As + sr * 64 + cs * 8);
        }
        #pragma unroll
        for (int n = 0; n < 4; ++n) {
            int r  = wc * 64 + n * 16 + (lane & 15);
            int sr = r >> 1;
            int c  = ((r & 1) << 2) | (lane >> 4);
            int cs = c ^ (sr & 7);
            bfr[n] = *(const s16x8*)(Bs + sr * 64 + cs * 8);
        }
        #pragma unroll
        for (int m = 0; m < 4; ++m)
            #pragma unroll
            for (int n = 0; n < 4; ++n)
                acc[m][n] = __builtin_amdgcn_mfma_f32_16x16x32_bf16(af[m], bfr[n], acc[m][n], 0, 0, 0);

        __syncthreads();
    }

    // C/D: col=lane&15, row=(lane>>4)*4+reg (m89-verified)
    #pragma unroll
    for (int m = 0; m < 4; ++m) {
        int row = rowBase + wr * 64 + m * 16 + ((lane >> 4) << 2);
        #pragma unroll
        for (int n = 0; n < 4; ++n) {
            int col = colBase + wc * 64 + n * 16 + (lane & 15);
            if (BF16OUT) {
                s16* cp = (s16*)Cv + (size_t)row * Ndim + col;
                #pragma unroll
                for (int j = 0; j < 4; ++j)
                    cp[(size_t)j * Ndim] = f2bs(acc[m][n][j]);
            } else {
                float* cp = (float*)Cv + (size_t)row * Ndim + col;
                #pragma unroll
                for (int j = 0; j < 4; ++j)
                    cp[(size_t)j * Ndim] = acc[m][n][j];
            }
        }
    }
}

// ---------- RoPE in-place on bf16, 8 j-values per thread ----------
__global__ __launch_bounds__(256) void rope_kernel(s16* __restrict__ X, int nHmask,
                                                   int rowShift, int rowStride,
                                                   float scale, int total) {
    int idx = blockIdx.x * 256 + threadIdx.x;
    if (idx >= total) return;
    int jc  = idx & 7;                 // j-chunk of 8
    int hh  = (idx >> 3) & nHmask;
    int row = idx >> rowShift;
    int s   = row & (S - 1);

    s16* base = X + (size_t)row * rowStride + hh * HD;
    s16x8 a = *(const s16x8*)(base + jc * 8);
    s16x8 b = *(const s16x8*)(base + 64 + jc * 8);
    s16x8 na, nb;
    #pragma unroll
    for (int i = 0; i < 8; ++i) {
        int j = jc * 8 + i;
        float f = (float)s * exp2f(-(float)j * 0.2076205059302203f);  // s*10000^(-j/64)
        float sn, c;
        __sincosf(f, &sn, &c);
        float x1 = bs2f(a[i]), x2 = bs2f(b[i]);
        na[i] = f2bs((x1 * c - x2 * sn) * scale);
        nb[i] = f2bs((x2 * c + x1 * sn) * scale);
    }
    *(s16x8*)(base + jc * 8) = na;
    *(s16x8*)(base + 64 + jc * 8) = nb;
}

// ---------- V transpose: KVb[M][1024] (V at col 512+kvh*128+d) -> VT[b][kvh][128][S] ----------
__global__ __launch_bounds__(256) void vtrans(const s16* __restrict__ KVb,
                                              s16* __restrict__ VT) {
    __shared__ s16 tl[64][72];
    const int t  = threadIdx.x;
    const int c8 = (t & 7) * 8;
    const int r  = t >> 3;
    const int s0 = blockIdx.x * 64;
    const int z  = blockIdx.y;
    const int bk = z >> 1;
    const int d0 = (z & 1) * 64;
    const int b  = bk >> 2, kvh = bk & 3;

    #pragma unroll
    for (int i = 0; i < 2; ++i) {
        int row = r + i * 32;
        *(s16x8*)&tl[row][c8] =
            *(const s16x8*)(KVb + (size_t)(b * S + s0 + row) * 1024 + 512 + kvh * HD + d0 + c8);
    }
    __syncthreads();
    #pragma unroll
    for (int i = 0; i < 2; ++i) {
        int drow = r + i * 32;
        s16x8 v;
        #pragma unroll
        for (int k = 0; k < 8; ++k) v[k] = tl[c8 + k][drow];
        *(s16x8*)(VT + (size_t)(bk * 128 + d0 + drow) * S + s0 + c8) = v;
    }
}

// ---------- MFMA flash attention, 32-row q-tile/wave, 64-kv tiles, reg-staged pipeline ----------
// Block: 4 waves = 4 q-heads of one kv-group, same 32 q-rows. grid = B*NKV*(S/32) = 512.
// NO VGPR cap (round-6 spilled at 128-cap: WRITE_SIZE 177MB of scratch). ~200 VGPRs
// -> 8 waves/CU naturally. QK->softmax split per tq to shrink sv liveness.
// T13 defer-max: skip O-rescale unless row max grows by >8.
__global__ __launch_bounds__(256) void attn_mfma(const s16* __restrict__ Q,
                                                 const s16* __restrict__ KV,
                                                 const s16* __restrict__ VT,
                                                 s16* __restrict__ O) {
    __shared__ __align__(16) s16 Kl[64 * 128];
    __shared__ __align__(16) s16 Vl[128 * 64];
    __shared__ __align__(16) s16 Pl[4][32 * 72];

    const int t    = threadIdx.x;
    const int lane = t & 63;
    const int wid  = t >> 6;
    const int g    = lane >> 4;
    const int cc   = lane & 15;
    const int bid  = blockIdx.x;
    const int qt   = bid & 63;
    const int kvh  = (bid >> 6) & 3;
    const int b    = bid >> 8;
    const int qbase = qt * 32;
    const int h    = kvh * 4 + wid;

    // Q A-frags: 2 row-tiles x 4 k-chunks
    s16x8 qf[2][4];
    #pragma unroll
    for (int tq = 0; tq < 2; ++tq)
        #pragma unroll
        for (int kc = 0; kc < 4; ++kc)
            qf[tq][kc] = *(const s16x8*)(Q + (size_t)(b * S + qbase + tq * 16 + cc) * 2048
                                           + h * HD + kc * 32 + g * 8);

    float m_[2][4], l_[2][4];
    f32x4 o_[2][8];
    #pragma unroll
    for (int tq = 0; tq < 2; ++tq) {
        #pragma unroll
        for (int j = 0; j < 4; ++j) { m_[tq][j] = -1e30f; l_[tq][j] = 0.f; }
        #pragma unroll
        for (int dt = 0; dt < 8; ++dt) o_[tq][dt] = (f32x4)0.f;
    }

    const int kvstart = qbase >= WIN ? qbase - WIN : 0;
    const int nt = (qbase + 32 - kvstart + 63) >> 6;

    int4 kreg[4], vreg[4];
    auto load_tile = [&](int kvb) {
        #pragma unroll
        for (int i = 0; i < 4; ++i) {
            int lc = i * 256 + t;              // K chunk 0..1023
            int r = lc >> 4, sl = lc & 15;
            int ch = sl ^ (r & 15);
            int kvr = kvb + r; if (kvr > S - 1) kvr = S - 1;
            kreg[i] = *(const int4*)(KV + (size_t)(b * S + kvr) * 1024 + kvh * HD + ch * 8);
        }
        #pragma unroll
        for (int i = 0; i < 4; ++i) {
            int lc = i * 256 + t;              // V chunk 0..1023
            int d = lc >> 3, sl = lc & 7;
            int ch = sl ^ (d & 7);
            int col = kvb + ch * 8; if (col > S - 8) col = S - 8;
            vreg[i] = *(const int4*)(VT + (size_t)((b * 4 + kvh) * HD + d) * S + col);
        }
    };
    auto write_tile = [&]() {
        #pragma unroll
        for (int i = 0; i < 4; ++i) {
            *(int4*)((char*)Kl + (size_t)(i * 256 + t) * 16) = kreg[i];
            *(int4*)((char*)Vl + (size_t)(i * 256 + t) * 16) = vreg[i];
        }
    };

    load_tile(kvstart);
    write_tile();
    __syncthreads();

    for (int it = 0; it < nt; ++it) {
        const int kvb = kvstart + it * 64;
        if (it + 1 < nt) load_tile(kvb + 64);   // global->reg: latency hides under compute

        // ---- per q-subtile: QK^T then softmax (halves sv liveness) ----
        #pragma unroll
        for (int tq = 0; tq < 2; ++tq) {
            f32x4 sv[4];
            #pragma unroll
            for (int n = 0; n < 4; ++n) sv[n] = (f32x4)0.f;
            #pragma unroll
            for (int n = 0; n < 4; ++n) {
                int r = n * 16 + cc;
                #pragma unroll
                for (int kc = 0; kc < 4; ++kc) {
                    int sl = (kc * 4 + g) ^ (r & 15);
                    s16x8 kf = *(const s16x8*)(Kl + r * 128 + sl * 8);
                    sv[n] = __builtin_amdgcn_mfma_f32_16x16x32_bf16(qf[tq][kc], kf, sv[n], 0, 0, 0);
                }
            }

            // pass 1: row maxes + defer-max vote (row q=qbase+tq*16+4g+j)
            float mx4[4];
            bool need = false;
            #pragma unroll
            for (int j = 0; j < 4; ++j) {
                int qp = qbase + tq * 16 + 4 * g + j;
                float mx = -1e30f;
                #pragma unroll
                for (int n = 0; n < 4; ++n) {
                    int dist = qp - (kvb + n * 16 + cc);
                    float sc = (dist >= 0 && dist <= WIN) ? sv[n][j] : -1e30f;
                    mx = fmaxf(mx, sc);
                }
                #pragma unroll
                for (int off = 1; off < 16; off <<= 1) mx = fmaxf(mx, __shfl_xor(mx, off));
                mx4[j] = mx;
                need |= (mx > m_[tq][j] + 8.f);
            }
            if (__ballot(need) != 0ull) {   // T13: rescale only when max grew
                #pragma unroll
                for (int j = 0; j < 4; ++j) {
                    float mn = fmaxf(m_[tq][j], mx4[j]);
                    float a  = __expf(m_[tq][j] - mn);
                    m_[tq][j] = mn;
                    l_[tq][j] *= a;
                    #pragma unroll
                    for (int dt = 0; dt < 8; ++dt) o_[tq][dt][j] *= a;
                }
            }
            // pass 2: exponentiate (bounded by e^8), P->LDS, l accumulate
            #pragma unroll
            for (int j = 0; j < 4; ++j) {
                int qp = qbase + tq * 16 + 4 * g + j;
                float ps = 0.f;
                int row = tq * 16 + 4 * g + j;
                #pragma unroll
                for (int n = 0; n < 4; ++n) {
                    int dist = qp - (kvb + n * 16 + cc);
                    float sc = (dist >= 0 && dist <= WIN) ? sv[n][j] : -1e30f;
                    float pv = __expf(sc - m_[tq][j]);
                    ps += pv;
                    Pl[wid][row * 72 + n * 16 + cc] = f2bs(pv);
                }
                #pragma unroll
                for (int off = 1; off < 16; off <<= 1) ps += __shfl_xor(ps, off);
                l_[tq][j] += ps;
            }
        }

        // ---- PV: O[32q][128d] += P[32q][64kv] @ V[64kv][128d] (P per-wave: no barrier) ----
        #pragma unroll
        for (int ks = 0; ks < 2; ++ks) {
            s16x8 pa0 = *(const s16x8*)(&Pl[wid][(0  + cc) * 72 + ks * 32 + g * 8]);
            s16x8 pa1 = *(const s16x8*)(&Pl[wid][(16 + cc) * 72 + ks * 32 + g * 8]);
            #pragma unroll
            for (int dt = 0; dt < 8; ++dt) {
                int d = dt * 16 + cc;
                int sl = (ks * 4 + g) ^ (d & 7);
                s16x8 vf = *(const s16x8*)(Vl + d * 64 + sl * 8);
                o_[0][dt] = __builtin_amdgcn_mfma_f32_16x16x32_bf16(pa0, vf, o_[0][dt], 0, 0, 0);
                o_[1][dt] = __builtin_amdgcn_mfma_f32_16x16x32_bf16(pa1, vf, o_[1][dt], 0, 0, 0);
            }
        }

        __syncthreads();               // all K/V LDS reads done
        if (it + 1 < nt) {
            write_tile();              // regs (arrived during compute) -> LDS
            __syncthreads();
        }
    }

    // ---- normalize + store ----
    #pragma unroll
    for (int tq = 0; tq < 2; ++tq) {
        #pragma unroll
        for (int j = 0; j < 4; ++j) {
            float inv = 1.0f / l_[tq][j];
            size_t rb = (size_t)(b * S + qbase + tq * 16 + 4 * g + j) * 2048 + h * HD;
            #pragma unroll
            for (int dt = 0; dt < 8; ++dt)
                O[rb + dt * 16 + cc] = f2bs(o_[tq][dt][j] * inv);
        }
    }
}

}  // namespace

extern "C" void kernel_launch(void* const* d_in, const int* in_sizes, int n_in,
                              void* d_out, int out_size, void* d_ws, size_t ws_size,
                              hipStream_t stream) {
    const float* hs = (const float*)d_in[0];
    const float* Wq = (const float*)d_in[1];
    const float* Wk = (const float*)d_in[2];
    const float* Wv = (const float*)d_in[3];
    const float* Wo = (const float*)d_in[4];
    float* out = (float*)d_out;

    char* p = (char*)d_ws;
    s16* hsb  = (s16*)p;  p += (size_t)M * 2048 * 2;
    s16* WqT  = (s16*)p;  p += (size_t)2048 * 2048 * 2;
    s16* WkvT = (s16*)p;  p += (size_t)1024 * 2048 * 2;
    s16* WoT  = (s16*)p;  p += (size_t)2048 * 2048 * 2;
    s16* Qb   = (s16*)p;  p += (size_t)M * 2048 * 2;
    s16* KVb  = (s16*)p;  p += (size_t)M * 1024 * 2;
    s16* VT   = (s16*)p;
    s16* AOb  = hsb;   // reuse after projections

    dim3 blk(256);
    const float qscale = 0.08838834764831845f;  // 1/sqrt(128)

    cast_kernel<<<(M * H / 8 + 255) / 256, blk, 0, stream>>>(hs, hsb, M * H / 8);
    transpose_cast<<<dim3(2048 / 64, 2048 / 64), blk, 0, stream>>>(Wq, WqT, 2048, 2048);
    transpose_cast<<<dim3(512 / 64, 2048 / 64), blk, 0, stream>>>(Wk, WkvT, 2048, 512);
    transpose_cast<<<dim3(512 / 64, 2048 / 64), blk, 0, stream>>>(Wv, WkvT + (size_t)512 * 2048, 2048, 512);
    transpose_cast<<<dim3(2048 / 64, 2048 / 64), blk, 0, stream>>>(Wo, WoT, 2048, 2048);

    gemm_bf16<true><<<dim3(2048 / 128, M / 128), blk, 0, stream>>>(hsb, WqT, Qb, 2048, 2048);
    gemm_bf16<true><<<dim3(1024 / 128, M / 128), blk, 0, stream>>>(hsb, WkvT, KVb, 1024, 2048);

    rope_kernel<<<(M * NH * 8) / 256, blk, 0, stream>>>(Qb, 15, 7, 2048, qscale, M * NH * 8);
    rope_kernel<<<(M * NKV * 8) / 256, blk, 0, stream>>>(KVb, 3, 5, 1024, 1.0f, M * NKV * 8);

    vtrans<<<dim3(S / 64, B * NKV * 2), blk, 0, stream>>>(KVb, VT);

    attn_mfma<<<B * NKV * (S / 32), blk, 0, stream>>>(Qb, KVb, VT, AOb);

    gemm_bf16<false><<<dim3(2048 / 128, M / 128), blk, 0, stream>>>(AOb, WoT, out, 2048, 2048);
}

// Round 11
// 360.742 us; speedup vs baseline: 1.4165x; 1.4165x over previous
//
#include <hip/hip_runtime.h>
#include <math.h>

namespace {

typedef short s16;
typedef short s16x8 __attribute__((ext_vector_type(8)));
typedef float f32x4 __attribute__((ext_vector_type(4)));

constexpr int B   = 2;
constexpr int S   = 2048;
constexpr int H   = 2048;
constexpr int NH  = 16;
constexpr int NKV = 4;
constexpr int HD  = 128;
constexpr int WIN = 1024;
constexpr int M   = B * S;       // 4096

// ---- fp32 -> bf16 (RNE) as raw short ----
__device__ inline s16 f2bs(float x) {
    unsigned u = __float_as_uint(x);
    u += 0x7fffu + ((u >> 16) & 1u);
    return (s16)(u >> 16);
}
// ---- bf16 bits -> fp32 ----
__device__ inline float bs2f(s16 v) {
    return __uint_as_float(((unsigned)(unsigned short)v) << 16);
}

__device__ inline void gload_lds16(const void* g, void* l) {
    __builtin_amdgcn_global_load_lds(
        (const __attribute__((address_space(1))) void*)g,
        (__attribute__((address_space(3))) void*)l, 16, 0, 0);
}

// ---------- fp32 -> bf16 cast, 8 elems/thread ----------
__global__ __launch_bounds__(256) void cast_kernel(const float* __restrict__ X,
                                                   s16* __restrict__ Y, int n8) {
    int i = blockIdx.x * 256 + threadIdx.x;
    if (i >= n8) return;
    const float4* p = (const float4*)X + (size_t)i * 2;
    float4 a = p[0], b = p[1];
    s16x8 v;
    v[0] = f2bs(a.x); v[1] = f2bs(a.y); v[2] = f2bs(a.z); v[3] = f2bs(a.w);
    v[4] = f2bs(b.x); v[5] = f2bs(b.y); v[6] = f2bs(b.z); v[7] = f2bs(b.w);
    *(s16x8*)(Y + (size_t)i * 8) = v;
}

// ---------- W[K][N] fp32 -> WT[N][K] bf16 ----------
__global__ __launch_bounds__(256) void transpose_cast(const float* __restrict__ W,
                                                      s16* __restrict__ WT,
                                                      int K, int N) {
    __shared__ float tile[64][65];
    int c = threadIdx.x & 63, r4 = threadIdx.x >> 6;
    int nb = blockIdx.x * 64, kb = blockIdx.y * 64;
    #pragma unroll
    for (int i = 0; i < 16; ++i) {
        int r = r4 + i * 4;
        tile[r][c] = W[(size_t)(kb + r) * N + nb + c];
    }
    __syncthreads();
    #pragma unroll
    for (int i = 0; i < 16; ++i) {
        int r = r4 + i * 4;
        WT[(size_t)(nb + r) * K + kb + c] = f2bs(tile[c][r]);
    }
}

// ---------- bf16 MFMA GEMM: C[M,N] = A[M,K] @ BT[N,K]^T ----------
// 128x128 tile, BK=32, 4 waves (2x2), 4x4 16x16x32 frags per wave.
// LDS XOR-swizzled at 16B granularity (superrow=128B, slot'=slot^(sr&7)).
template <bool BF16OUT>
__global__ __launch_bounds__(256) void gemm_bf16(const s16* __restrict__ A,
                                                 const s16* __restrict__ BT,
                                                 void* __restrict__ Cv,
                                                 int Ndim, int Kdim) {
    __shared__ __align__(16) s16 As[128 * 32];
    __shared__ __align__(16) s16 Bs[128 * 32];

    const int t    = threadIdx.x;
    const int lane = t & 63;
    const int wid  = t >> 6;
    const int wr   = wid >> 1;
    const int wc   = wid & 1;
    const int rowBase = blockIdx.y * 128;
    const int colBase = blockIdx.x * 128;

    const s16* Ab = A  + (size_t)rowBase * Kdim;
    const s16* Bb = BT + (size_t)colBase * Kdim;

    f32x4 acc[4][4];
    #pragma unroll
    for (int m = 0; m < 4; ++m)
        #pragma unroll
        for (int n = 0; n < 4; ++n)
            acc[m][n] = (f32x4)0.f;

    for (int k0 = 0; k0 < Kdim; k0 += 32) {
        #pragma unroll
        for (int i = 0; i < 2; ++i) {
            int lc = i * 256 + t;             // 16B chunk 0..511
            int sr = lc >> 3;                 // 128B superrow
            int cc = (lc & 7) ^ (sr & 7);     // source chunk in superrow
            int r  = (sr << 1) | (cc >> 2);
            int kg = cc & 3;
            const s16* ga = Ab + (size_t)r * Kdim + k0 + kg * 8;
            const s16* gb = Bb + (size_t)r * Kdim + k0 + kg * 8;
            char* la = (char*)As + i * 4096 + wid * 1024;
            char* lb = (char*)Bs + i * 4096 + wid * 1024;
            gload_lds16(ga, la);
            gload_lds16(gb, lb);
        }
        __syncthreads();

        s16x8 af[4], bfr[4];
        #pragma unroll
        for (int m = 0; m < 4; ++m) {
            int r  = wr * 64 + m * 16 + (lane & 15);
            int sr = r >> 1;
            int c  = ((r & 1) << 2) | (lane >> 4);
            int cs = c ^ (sr & 7);
            af[m] = *(const s16x8*)(As + sr * 64 + cs * 8);
        }
        #pragma unroll
        for (int n = 0; n < 4; ++n) {
            int r  = wc * 64 + n * 16 + (lane & 15);
            int sr = r >> 1;
            int c  = ((r & 1) << 2) | (lane >> 4);
            int cs = c ^ (sr & 7);
            bfr[n] = *(const s16x8*)(Bs + sr * 64 + cs * 8);
        }
        #pragma unroll
        for (int m = 0; m < 4; ++m)
            #pragma unroll
            for (int n = 0; n < 4; ++n)
                acc[m][n] = __builtin_amdgcn_mfma_f32_16x16x32_bf16(af[m], bfr[n], acc[m][n], 0, 0, 0);

        __syncthreads();
    }

    // C/D: col=lane&15, row=(lane>>4)*4+reg (m89-verified)
    #pragma unroll
    for (int m = 0; m < 4; ++m) {
        int row = rowBase + wr * 64 + m * 16 + ((lane >> 4) << 2);
        #pragma unroll
        for (int n = 0; n < 4; ++n) {
            int col = colBase + wc * 64 + n * 16 + (lane & 15);
            if (BF16OUT) {
                s16* cp = (s16*)Cv + (size_t)row * Ndim + col;
                #pragma unroll
                for (int j = 0; j < 4; ++j)
                    cp[(size_t)j * Ndim] = f2bs(acc[m][n][j]);
            } else {
                float* cp = (float*)Cv + (size_t)row * Ndim + col;
                #pragma unroll
                for (int j = 0; j < 4; ++j)
                    cp[(size_t)j * Ndim] = acc[m][n][j];
            }
        }
    }
}

// ---------- RoPE in-place on bf16, 8 j-values per thread ----------
__global__ __launch_bounds__(256) void rope_kernel(s16* __restrict__ X, int nHmask,
                                                   int rowShift, int rowStride,
                                                   float scale, int total) {
    int idx = blockIdx.x * 256 + threadIdx.x;
    if (idx >= total) return;
    int jc  = idx & 7;                 // j-chunk of 8
    int hh  = (idx >> 3) & nHmask;
    int row = idx >> rowShift;
    int s   = row & (S - 1);

    s16* base = X + (size_t)row * rowStride + hh * HD;
    s16x8 a = *(const s16x8*)(base + jc * 8);
    s16x8 b = *(const s16x8*)(base + 64 + jc * 8);
    s16x8 na, nb;
    #pragma unroll
    for (int i = 0; i < 8; ++i) {
        int j = jc * 8 + i;
        float f = (float)s * exp2f(-(float)j * 0.2076205059302203f);  // s*10000^(-j/64)
        float sn, c;
        __sincosf(f, &sn, &c);
        float x1 = bs2f(a[i]), x2 = bs2f(b[i]);
        na[i] = f2bs((x1 * c - x2 * sn) * scale);
        nb[i] = f2bs((x2 * c + x1 * sn) * scale);
    }
    *(s16x8*)(base + jc * 8) = na;
    *(s16x8*)(base + 64 + jc * 8) = nb;
}

// ---------- V transpose: KVb[M][1024] (V at col 512+kvh*128+d) -> VT[b][kvh][128][S] ----------
__global__ __launch_bounds__(256) void vtrans(const s16* __restrict__ KVb,
                                              s16* __restrict__ VT) {
    __shared__ s16 tl[64][72];
    const int t  = threadIdx.x;
    const int c8 = (t & 7) * 8;
    const int r  = t >> 3;
    const int s0 = blockIdx.x * 64;
    const int z  = blockIdx.y;
    const int bk = z >> 1;
    const int d0 = (z & 1) * 64;
    const int b  = bk >> 2, kvh = bk & 3;

    #pragma unroll
    for (int i = 0; i < 2; ++i) {
        int row = r + i * 32;
        *(s16x8*)&tl[row][c8] =
            *(const s16x8*)(KVb + (size_t)(b * S + s0 + row) * 1024 + 512 + kvh * HD + d0 + c8);
    }
    __syncthreads();
    #pragma unroll
    for (int i = 0; i < 2; ++i) {
        int drow = r + i * 32;
        s16x8 v;
        #pragma unroll
        for (int k = 0; k < 8; ++k) v[k] = tl[c8 + k][drow];
        *(s16x8*)(VT + (size_t)(bk * 128 + d0 + drow) * S + s0 + c8) = v;
    }
}

// ---------- MFMA flash attention ----------
// Block: 4 waves = 4 q-heads of one kv-group, same 32 q-rows. grid = B*NKV*(S/32) = 512.
// K/V staged via global_load_lds direct (linear LDS dest, pre-swizzled source; the
// round-4 zero-spill mechanism) with 32q/64kv tiles (round-6 geometry).
// K LDS [64][128] slot^(r&15); V LDS [128][64] slot^(d&7). P per-wave (no barrier).
// K-frags shared across both q-subtiles (halves QK ds_reads). Interior tiles skip
// the mask entirely (wave-uniform). T13 defer-max gates the O-rescale.
__global__ __launch_bounds__(256, 2) void attn_mfma(const s16* __restrict__ Q,
                                                    const s16* __restrict__ KV,
                                                    const s16* __restrict__ VT,
                                                    s16* __restrict__ O) {
    __shared__ __align__(16) s16 Kl[64 * 128];
    __shared__ __align__(16) s16 Vl[128 * 64];
    __shared__ __align__(16) s16 Pl[4][32 * 72];

    const int t    = threadIdx.x;
    const int lane = t & 63;
    const int wid  = t >> 6;
    const int g    = lane >> 4;
    const int cc   = lane & 15;
    const int bid  = blockIdx.x;
    const int qt   = bid & 63;
    const int kvh  = (bid >> 6) & 3;
    const int b    = bid >> 8;
    const int qbase = qt * 32;
    const int h    = kvh * 4 + wid;

    // Q A-frags: 2 row-tiles x 4 k-chunks (32 VGPRs, live whole kernel)
    s16x8 qf[2][4];
    #pragma unroll
    for (int tq = 0; tq < 2; ++tq)
        #pragma unroll
        for (int kc = 0; kc < 4; ++kc)
            qf[tq][kc] = *(const s16x8*)(Q + (size_t)(b * S + qbase + tq * 16 + cc) * 2048
                                           + h * HD + kc * 32 + g * 8);

    float m_[2][4], l_[2][4];
    f32x4 o_[2][8];
    #pragma unroll
    for (int tq = 0; tq < 2; ++tq) {
        #pragma unroll
        for (int j = 0; j < 4; ++j) { m_[tq][j] = -1e30f; l_[tq][j] = 0.f; }
        #pragma unroll
        for (int dt = 0; dt < 8; ++dt) o_[tq][dt] = (f32x4)0.f;
    }

    const int kvstart = qbase >= WIN ? qbase - WIN : 0;
    const int nt = (qbase + 32 - kvstart + 63) >> 6;

    for (int it = 0; it < nt; ++it) {
        const int kvb = kvstart + it * 64;

        // ---- stage K (16KB) + V (16KB) via async global->LDS, pre-swizzled source ----
        #pragma unroll
        for (int i = 0; i < 4; ++i) {
            int lc = i * 256 + t;
            {   // K: row r = 256B = 16 slots; source chunk = slot ^ (r&15)
                int r = lc >> 4, sl = lc & 15;
                int ch = sl ^ (r & 15);
                int kvr = kvb + r; if (kvr > S - 1) kvr = S - 1;
                gload_lds16(KV + (size_t)(b * S + kvr) * 1024 + kvh * HD + ch * 8,
                            (char*)Kl + i * 4096 + wid * 1024);
            }
            {   // V: row d = 128B = 8 slots; source chunk = slot ^ (d&7)
                int d = lc >> 3, sl = lc & 7;
                int ch = sl ^ (d & 7);
                int col = kvb + ch * 8; if (col > S - 8) col = S - 8;
                gload_lds16(VT + (size_t)((b * 4 + kvh) * HD + d) * S + col,
                            (char*)Vl + i * 4096 + wid * 1024);
            }
        }
        __syncthreads();   // drains vmcnt before barrier

        // ---- QK^T: S[32q][64kv]; kf shared by both q-subtiles ----
        f32x4 sv[2][4];
        #pragma unroll
        for (int tq = 0; tq < 2; ++tq)
            #pragma unroll
            for (int n = 0; n < 4; ++n) sv[tq][n] = (f32x4)0.f;
        #pragma unroll
        for (int n = 0; n < 4; ++n) {
            int r = n * 16 + cc;
            #pragma unroll
            for (int kc = 0; kc < 4; ++kc) {
                int sl = (kc * 4 + g) ^ (r & 15);
                s16x8 kf = *(const s16x8*)(Kl + r * 128 + sl * 8);
                sv[0][n] = __builtin_amdgcn_mfma_f32_16x16x32_bf16(qf[0][kc], kf, sv[0][n], 0, 0, 0);
                sv[1][n] = __builtin_amdgcn_mfma_f32_16x16x32_bf16(qf[1][kc], kf, sv[1][n], 0, 0, 0);
            }
        }

        // ---- mask only on boundary tiles (wave-uniform branch) ----
        if (kvb + 63 > qbase || kvb < qbase + 31 - WIN) {
            #pragma unroll
            for (int tq = 0; tq < 2; ++tq)
                #pragma unroll
                for (int j = 0; j < 4; ++j) {
                    int qp = qbase + tq * 16 + 4 * g + j;
                    #pragma unroll
                    for (int n = 0; n < 4; ++n) {
                        int dist = qp - (kvb + n * 16 + cc);
                        if (!(dist >= 0 && dist <= WIN)) sv[tq][n][j] = -1e30f;
                    }
                }
        }

        // ---- online softmax per q-subtile (row q=qbase+tq*16+4g+j) ----
        #pragma unroll
        for (int tq = 0; tq < 2; ++tq) {
            float mx4[4];
            bool need = false;
            #pragma unroll
            for (int j = 0; j < 4; ++j) {
                float mx = fmaxf(fmaxf(sv[tq][0][j], sv[tq][1][j]),
                                 fmaxf(sv[tq][2][j], sv[tq][3][j]));
                #pragma unroll
                for (int off = 1; off < 16; off <<= 1) mx = fmaxf(mx, __shfl_xor(mx, off));
                mx4[j] = mx;
                need |= (mx > m_[tq][j] + 8.f);
            }
            if (__ballot(need) != 0ull) {   // T13: rescale only when max grew enough
                #pragma unroll
                for (int j = 0; j < 4; ++j) {
                    float mn = fmaxf(m_[tq][j], mx4[j]);
                    float a  = __expf(m_[tq][j] - mn);
                    m_[tq][j] = mn;
                    l_[tq][j] *= a;
                    #pragma unroll
                    for (int dt = 0; dt < 8; ++dt) o_[tq][dt][j] *= a;
                }
            }
            #pragma unroll
            for (int j = 0; j < 4; ++j) {
                int row = tq * 16 + 4 * g + j;
                float ps = 0.f;
                #pragma unroll
                for (int n = 0; n < 4; ++n) {
                    float pv = __expf(sv[tq][n][j] - m_[tq][j]);  // bounded by e^8
                    ps += pv;
                    Pl[wid][row * 72 + n * 16 + cc] = f2bs(pv);
                }
                #pragma unroll
                for (int off = 1; off < 16; off <<= 1) ps += __shfl_xor(ps, off);
                l_[tq][j] += ps;
            }
        }

        // ---- PV: O[32q][128d] += P[32q][64kv] @ V[64kv][128d] ----
        #pragma unroll
        for (int ks = 0; ks < 2; ++ks) {
            s16x8 pa0 = *(const s16x8*)(&Pl[wid][(0  + cc) * 72 + ks * 32 + g * 8]);
            s16x8 pa1 = *(const s16x8*)(&Pl[wid][(16 + cc) * 72 + ks * 32 + g * 8]);
            #pragma unroll
            for (int dt = 0; dt < 8; ++dt) {
                int d = dt * 16 + cc;
                int sl = (ks * 4 + g) ^ (d & 7);
                s16x8 vf = *(const s16x8*)(Vl + d * 64 + sl * 8);
                o_[0][dt] = __builtin_amdgcn_mfma_f32_16x16x32_bf16(pa0, vf, o_[0][dt], 0, 0, 0);
                o_[1][dt] = __builtin_amdgcn_mfma_f32_16x16x32_bf16(pa1, vf, o_[1][dt], 0, 0, 0);
            }
        }

        __syncthreads();   // K/V LDS reads done before next stage
    }

    // ---- normalize + store ----
    #pragma unroll
    for (int tq = 0; tq < 2; ++tq) {
        #pragma unroll
        for (int j = 0; j < 4; ++j) {
            float inv = 1.0f / l_[tq][j];
            size_t rb = (size_t)(b * S + qbase + tq * 16 + 4 * g + j) * 2048 + h * HD;
            #pragma unroll
            for (int dt = 0; dt < 8; ++dt)
                O[rb + dt * 16 + cc] = f2bs(o_[tq][dt][j] * inv);
        }
    }
}

}  // namespace

extern "C" void kernel_launch(void* const* d_in, const int* in_sizes, int n_in,
                              void* d_out, int out_size, void* d_ws, size_t ws_size,
                              hipStream_t stream) {
    const float* hs = (const float*)d_in[0];
    const float* Wq = (const float*)d_in[1];
    const float* Wk = (const float*)d_in[2];
    const float* Wv = (const float*)d_in[3];
    const float* Wo = (const float*)d_in[4];
    float* out = (float*)d_out;

    char* p = (char*)d_ws;
    s16* hsb  = (s16*)p;  p += (size_t)M * 2048 * 2;
    s16* WqT  = (s16*)p;  p += (size_t)2048 * 2048 * 2;
    s16* WkvT = (s16*)p;  p += (size_t)1024 * 2048 * 2;
    s16* WoT  = (s16*)p;  p += (size_t)2048 * 2048 * 2;
    s16* Qb   = (s16*)p;  p += (size_t)M * 2048 * 2;
    s16* KVb  = (s16*)p;  p += (size_t)M * 1024 * 2;
    s16* VT   = (s16*)p;
    s16* AOb  = hsb;   // reuse after projections

    dim3 blk(256);
    const float qscale = 0.08838834764831845f;  // 1/sqrt(128)

    cast_kernel<<<(M * H / 8 + 255) / 256, blk, 0, stream>>>(hs, hsb, M * H / 8);
    transpose_cast<<<dim3(2048 / 64, 2048 / 64), blk, 0, stream>>>(Wq, WqT, 2048, 2048);
    transpose_cast<<<dim3(512 / 64, 2048 / 64), blk, 0, stream>>>(Wk, WkvT, 2048, 512);
    transpose_cast<<<dim3(512 / 64, 2048 / 64), blk, 0, stream>>>(Wv, WkvT + (size_t)512 * 2048, 2048, 512);
    transpose_cast<<<dim3(2048 / 64, 2048 / 64), blk, 0, stream>>>(Wo, WoT, 2048, 2048);

    gemm_bf16<true><<<dim3(2048 / 128, M / 128), blk, 0, stream>>>(hsb, WqT, Qb, 2048, 2048);
    gemm_bf16<true><<<dim3(1024 / 128, M / 128), blk, 0, stream>>>(hsb, WkvT, KVb, 1024, 2048);

    rope_kernel<<<(M * NH * 8) / 256, blk, 0, stream>>>(Qb, 15, 7, 2048, qscale, M * NH * 8);
    rope_kernel<<<(M * NKV * 8) / 256, blk, 0, stream>>>(KVb, 3, 5, 1024, 1.0f, M * NKV * 8);

    vtrans<<<dim3(S / 64, B * NKV * 2), blk, 0, stream>>>(KVb, VT);

    attn_mfma<<<B * NKV * (S / 32), blk, 0, stream>>>(Qb, KVb, VT, AOb);

    gemm_bf16<false><<<dim3(2048 / 128, M / 128), blk, 0, stream>>>(AOb, WoT, out, 2048, 2048);
}

// Round 12
// 294.118 us; speedup vs baseline: 1.7374x; 1.2265x over previous
//
#include <hip/hip_runtime.h>
#include <math.h>

namespace {

typedef short s16;
typedef short s16x8 __attribute__((ext_vector_type(8)));
typedef float f32x4 __attribute__((ext_vector_type(4)));

constexpr int B   = 2;
constexpr int S   = 2048;
constexpr int H   = 2048;
constexpr int NH  = 16;
constexpr int NKV = 4;
constexpr int HD  = 128;
constexpr int WIN = 1024;
constexpr int M   = B * S;       // 4096
constexpr int QKVN = 3072;       // fused projection width: Q 2048 | K 512 | V 512

// ---- fp32 -> bf16 (RNE) as raw short ----
__device__ inline s16 f2bs(float x) {
    unsigned u = __float_as_uint(x);
    u += 0x7fffu + ((u >> 16) & 1u);
    return (s16)(u >> 16);
}
__device__ inline float bs2f(s16 v) {
    return __uint_as_float(((unsigned)(unsigned short)v) << 16);
}

__device__ inline void gload_lds16(const void* g, void* l) {
    __builtin_amdgcn_global_load_lds(
        (const __attribute__((address_space(1))) void*)g,
        (__attribute__((address_space(3))) void*)l, 16, 0, 0);
}

// ---------- fp32 -> bf16 cast, 8 elems/thread ----------
__global__ __launch_bounds__(256) void cast_kernel(const float* __restrict__ X,
                                                   s16* __restrict__ Y, int n8) {
    int i = blockIdx.x * 256 + threadIdx.x;
    if (i >= n8) return;
    const float4* p = (const float4*)X + (size_t)i * 2;
    float4 a = p[0], b = p[1];
    s16x8 v;
    v[0] = f2bs(a.x); v[1] = f2bs(a.y); v[2] = f2bs(a.z); v[3] = f2bs(a.w);
    v[4] = f2bs(b.x); v[5] = f2bs(b.y); v[6] = f2bs(b.z); v[7] = f2bs(b.w);
    *(s16x8*)(Y + (size_t)i * 8) = v;
}

// ---------- W[K][N] fp32 -> WT[N][K] bf16 ----------
__global__ __launch_bounds__(256) void transpose_cast(const float* __restrict__ W,
                                                      s16* __restrict__ WT,
                                                      int K, int N) {
    __shared__ float tile[64][65];
    int c = threadIdx.x & 63, r4 = threadIdx.x >> 6;
    int nb = blockIdx.x * 64, kb = blockIdx.y * 64;
    #pragma unroll
    for (int i = 0; i < 16; ++i) {
        int r = r4 + i * 4;
        tile[r][c] = W[(size_t)(kb + r) * N + nb + c];
    }
    __syncthreads();
    #pragma unroll
    for (int i = 0; i < 16; ++i) {
        int r = r4 + i * 4;
        WT[(size_t)(nb + r) * K + kb + c] = f2bs(tile[c][r]);
    }
}

// ---------- bf16 MFMA GEMM: C[M,N] = A[M,K] @ BT[N,K]^T ----------
// 128x128 tile, BK=64 (32 MFMA per barrier), 4 waves (2x2), 4x4 frags/wave.
// LDS [128][64] bf16: row = 128B = 8 x 16B chunks, chunk swizzle c^(r&7)
// (linear LDS dest for global_load_lds, pre-swizzled global source — rule 21).
// XCD-aware bijective block swizzle (nwg % 8 == 0 for all our grids).
template <bool BF16OUT>
__global__ __launch_bounds__(256, 2) void gemm_bf16(const s16* __restrict__ A,
                                                    const s16* __restrict__ BT,
                                                    void* __restrict__ Cv,
                                                    int Ndim, int Kdim) {
    __shared__ __align__(16) s16 As[128 * 64];
    __shared__ __align__(16) s16 Bs[128 * 64];

    const int t    = threadIdx.x;
    const int lane = t & 63;
    const int wid  = t >> 6;
    const int wr   = wid >> 1;
    const int wc   = wid & 1;

    // T1 XCD swizzle: contiguous chunk of row-major block order per XCD
    const int gx   = gridDim.x;
    const int nwg  = gx * gridDim.y;
    const int wgid = blockIdx.y * gx + blockIdx.x;
    const int swz  = (wgid & 7) * (nwg >> 3) + (wgid >> 3);
    const int rowBase = (swz / gx) * 128;
    const int colBase = (swz % gx) * 128;

    const s16* Ab = A  + (size_t)rowBase * Kdim;
    const s16* Bb = BT + (size_t)colBase * Kdim;

    f32x4 acc[4][4];
    #pragma unroll
    for (int m = 0; m < 4; ++m)
        #pragma unroll
        for (int n = 0; n < 4; ++n)
            acc[m][n] = (f32x4)0.f;

    for (int k0 = 0; k0 < Kdim; k0 += 64) {
        // stage A and B tiles (16 KB each): 1024 chunks of 16B per tile
        #pragma unroll
        for (int i = 0; i < 4; ++i) {
            int lc = i * 256 + t;             // chunk 0..1023
            int r  = lc >> 3;                 // row 0..127
            int sl = lc & 7;
            int ch = sl ^ (r & 7);            // pre-swizzled source chunk
            const s16* ga = Ab + (size_t)r * Kdim + k0 + ch * 8;
            const s16* gb = Bb + (size_t)r * Kdim + k0 + ch * 8;
            gload_lds16(ga, (char*)As + i * 4096 + wid * 1024);
            gload_lds16(gb, (char*)Bs + i * 4096 + wid * 1024);
        }
        __syncthreads();

        #pragma unroll
        for (int kk = 0; kk < 2; ++kk) {
            s16x8 af[4], bfr[4];
            #pragma unroll
            for (int m = 0; m < 4; ++m) {
                int r  = wr * 64 + m * 16 + (lane & 15);
                int c  = kk * 4 + (lane >> 4);
                int cs = c ^ (r & 7);
                af[m] = *(const s16x8*)(As + r * 64 + cs * 8);
            }
            #pragma unroll
            for (int n = 0; n < 4; ++n) {
                int r  = wc * 64 + n * 16 + (lane & 15);
                int c  = kk * 4 + (lane >> 4);
                int cs = c ^ (r & 7);
                bfr[n] = *(const s16x8*)(Bs + r * 64 + cs * 8);
            }
            #pragma unroll
            for (int m = 0; m < 4; ++m)
                #pragma unroll
                for (int n = 0; n < 4; ++n)
                    acc[m][n] = __builtin_amdgcn_mfma_f32_16x16x32_bf16(af[m], bfr[n], acc[m][n], 0, 0, 0);
        }

        __syncthreads();
    }

    // C/D: col=lane&15, row=(lane>>4)*4+reg (m89-verified)
    #pragma unroll
    for (int m = 0; m < 4; ++m) {
        int row = rowBase + wr * 64 + m * 16 + ((lane >> 4) << 2);
        #pragma unroll
        for (int n = 0; n < 4; ++n) {
            int col = colBase + wc * 64 + n * 16 + (lane & 15);
            if (BF16OUT) {
                s16* cp = (s16*)Cv + (size_t)row * Ndim + col;
                #pragma unroll
                for (int j = 0; j < 4; ++j)
                    cp[(size_t)j * Ndim] = f2bs(acc[m][n][j]);
            } else {
                float* cp = (float*)Cv + (size_t)row * Ndim + col;
                #pragma unroll
                for (int j = 0; j < 4; ++j)
                    cp[(size_t)j * Ndim] = acc[m][n][j];
            }
        }
    }
}

// ---------- RoPE in-place on bf16, 8 j-values per thread ----------
__global__ __launch_bounds__(256) void rope_kernel(s16* __restrict__ X, int nHmask,
                                                   int rowShift, int rowStride,
                                                   float scale, int total) {
    int idx = blockIdx.x * 256 + threadIdx.x;
    if (idx >= total) return;
    int jc  = idx & 7;                 // j-chunk of 8
    int hh  = (idx >> 3) & nHmask;
    int row = idx >> rowShift;
    int s   = row & (S - 1);

    s16* base = X + (size_t)row * rowStride + hh * HD;
    s16x8 a = *(const s16x8*)(base + jc * 8);
    s16x8 b = *(const s16x8*)(base + 64 + jc * 8);
    s16x8 na, nb;
    #pragma unroll
    for (int i = 0; i < 8; ++i) {
        int j = jc * 8 + i;
        float f = (float)s * exp2f(-(float)j * 0.2076205059302203f);  // s*10000^(-j/64)
        float sn, c;
        __sincosf(f, &sn, &c);
        float x1 = bs2f(a[i]), x2 = bs2f(b[i]);
        na[i] = f2bs((x1 * c - x2 * sn) * scale);
        nb[i] = f2bs((x2 * c + x1 * sn) * scale);
    }
    *(s16x8*)(base + jc * 8) = na;
    *(s16x8*)(base + 64 + jc * 8) = nb;
}

// ---------- V transpose: QKV[M][3072] (V at col 2560+kvh... actually VB pre-offset) ----------
// VB points at V region (col offset 2560 handled by caller): VB[row*3072 + kvh*128 + d]
__global__ __launch_bounds__(256) void vtrans(const s16* __restrict__ VB,
                                              s16* __restrict__ VT) {
    __shared__ s16 tl[64][72];
    const int t  = threadIdx.x;
    const int c8 = (t & 7) * 8;
    const int r  = t >> 3;
    const int s0 = blockIdx.x * 64;
    const int z  = blockIdx.y;
    const int bk = z >> 1;
    const int d0 = (z & 1) * 64;
    const int b  = bk >> 2, kvh = bk & 3;

    #pragma unroll
    for (int i = 0; i < 2; ++i) {
        int row = r + i * 32;
        *(s16x8*)&tl[row][c8] =
            *(const s16x8*)(VB + (size_t)(b * S + s0 + row) * QKVN + kvh * HD + d0 + c8);
    }
    __syncthreads();
    #pragma unroll
    for (int i = 0; i < 2; ++i) {
        int drow = r + i * 32;
        s16x8 v;
        #pragma unroll
        for (int k = 0; k < 8; ++k) v[k] = tl[c8 + k][drow];
        *(s16x8*)(VT + (size_t)(bk * 128 + d0 + drow) * S + s0 + c8) = v;
    }
}

// ---------- MFMA flash attention (R11-measured structure; only strides changed) ----------
// Q at QKV[row][h*128], K at QKV[row][2048 + kvh*128] (KB pre-offset by caller).
__global__ __launch_bounds__(256, 2) void attn_mfma(const s16* __restrict__ Q,
                                                    const s16* __restrict__ KB,
                                                    const s16* __restrict__ VT,
                                                    s16* __restrict__ O) {
    __shared__ __align__(16) s16 Kl[64 * 128];
    __shared__ __align__(16) s16 Vl[128 * 64];
    __shared__ __align__(16) s16 Pl[4][32 * 72];

    const int t    = threadIdx.x;
    const int lane = t & 63;
    const int wid  = t >> 6;
    const int g    = lane >> 4;
    const int cc   = lane & 15;
    const int bid  = blockIdx.x;
    const int qt   = bid & 63;
    const int kvh  = (bid >> 6) & 3;
    const int b    = bid >> 8;
    const int qbase = qt * 32;
    const int h    = kvh * 4 + wid;

    s16x8 qf[2][4];
    #pragma unroll
    for (int tq = 0; tq < 2; ++tq)
        #pragma unroll
        for (int kc = 0; kc < 4; ++kc)
            qf[tq][kc] = *(const s16x8*)(Q + (size_t)(b * S + qbase + tq * 16 + cc) * QKVN
                                           + h * HD + kc * 32 + g * 8);

    float m_[2][4], l_[2][4];
    f32x4 o_[2][8];
    #pragma unroll
    for (int tq = 0; tq < 2; ++tq) {
        #pragma unroll
        for (int j = 0; j < 4; ++j) { m_[tq][j] = -1e30f; l_[tq][j] = 0.f; }
        #pragma unroll
        for (int dt = 0; dt < 8; ++dt) o_[tq][dt] = (f32x4)0.f;
    }

    const int kvstart = qbase >= WIN ? qbase - WIN : 0;
    const int nt = (qbase + 32 - kvstart + 63) >> 6;

    for (int it = 0; it < nt; ++it) {
        const int kvb = kvstart + it * 64;

        #pragma unroll
        for (int i = 0; i < 4; ++i) {
            int lc = i * 256 + t;
            {   // K: row r = 256B = 16 slots; source chunk = slot ^ (r&15)
                int r = lc >> 4, sl = lc & 15;
                int ch = sl ^ (r & 15);
                int kvr = kvb + r; if (kvr > S - 1) kvr = S - 1;
                gload_lds16(KB + (size_t)(b * S + kvr) * QKVN + kvh * HD + ch * 8,
                            (char*)Kl + i * 4096 + wid * 1024);
            }
            {   // V: row d = 128B = 8 slots; source chunk = slot ^ (d&7)
                int d = lc >> 3, sl = lc & 7;
                int ch = sl ^ (d & 7);
                int col = kvb + ch * 8; if (col > S - 8) col = S - 8;
                gload_lds16(VT + (size_t)((b * 4 + kvh) * HD + d) * S + col,
                            (char*)Vl + i * 4096 + wid * 1024);
            }
        }
        __syncthreads();

        f32x4 sv[2][4];
        #pragma unroll
        for (int tq = 0; tq < 2; ++tq)
            #pragma unroll
            for (int n = 0; n < 4; ++n) sv[tq][n] = (f32x4)0.f;
        #pragma unroll
        for (int n = 0; n < 4; ++n) {
            int r = n * 16 + cc;
            #pragma unroll
            for (int kc = 0; kc < 4; ++kc) {
                int sl = (kc * 4 + g) ^ (r & 15);
                s16x8 kf = *(const s16x8*)(Kl + r * 128 + sl * 8);
                sv[0][n] = __builtin_amdgcn_mfma_f32_16x16x32_bf16(qf[0][kc], kf, sv[0][n], 0, 0, 0);
                sv[1][n] = __builtin_amdgcn_mfma_f32_16x16x32_bf16(qf[1][kc], kf, sv[1][n], 0, 0, 0);
            }
        }

        if (kvb + 63 > qbase || kvb < qbase + 31 - WIN) {
            #pragma unroll
            for (int tq = 0; tq < 2; ++tq)
                #pragma unroll
                for (int j = 0; j < 4; ++j) {
                    int qp = qbase + tq * 16 + 4 * g + j;
                    #pragma unroll
                    for (int n = 0; n < 4; ++n) {
                        int dist = qp - (kvb + n * 16 + cc);
                        if (!(dist >= 0 && dist <= WIN)) sv[tq][n][j] = -1e30f;
                    }
                }
        }

        #pragma unroll
        for (int tq = 0; tq < 2; ++tq) {
            float mx4[4];
            bool need = false;
            #pragma unroll
            for (int j = 0; j < 4; ++j) {
                float mx = fmaxf(fmaxf(sv[tq][0][j], sv[tq][1][j]),
                                 fmaxf(sv[tq][2][j], sv[tq][3][j]));
                #pragma unroll
                for (int off = 1; off < 16; off <<= 1) mx = fmaxf(mx, __shfl_xor(mx, off));
                mx4[j] = mx;
                need |= (mx > m_[tq][j] + 8.f);
            }
            if (__ballot(need) != 0ull) {
                #pragma unroll
                for (int j = 0; j < 4; ++j) {
                    float mn = fmaxf(m_[tq][j], mx4[j]);
                    float a  = __expf(m_[tq][j] - mn);
                    m_[tq][j] = mn;
                    l_[tq][j] *= a;
                    #pragma unroll
                    for (int dt = 0; dt < 8; ++dt) o_[tq][dt][j] *= a;
                }
            }
            #pragma unroll
            for (int j = 0; j < 4; ++j) {
                int row = tq * 16 + 4 * g + j;
                float ps = 0.f;
                #pragma unroll
                for (int n = 0; n < 4; ++n) {
                    float pv = __expf(sv[tq][n][j] - m_[tq][j]);
                    ps += pv;
                    Pl[wid][row * 72 + n * 16 + cc] = f2bs(pv);
                }
                #pragma unroll
                for (int off = 1; off < 16; off <<= 1) ps += __shfl_xor(ps, off);
                l_[tq][j] += ps;
            }
        }

        #pragma unroll
        for (int ks = 0; ks < 2; ++ks) {
            s16x8 pa0 = *(const s16x8*)(&Pl[wid][(0  + cc) * 72 + ks * 32 + g * 8]);
            s16x8 pa1 = *(const s16x8*)(&Pl[wid][(16 + cc) * 72 + ks * 32 + g * 8]);
            #pragma unroll
            for (int dt = 0; dt < 8; ++dt) {
                int d = dt * 16 + cc;
                int sl = (ks * 4 + g) ^ (d & 7);
                s16x8 vf = *(const s16x8*)(Vl + d * 64 + sl * 8);
                o_[0][dt] = __builtin_amdgcn_mfma_f32_16x16x32_bf16(pa0, vf, o_[0][dt], 0, 0, 0);
                o_[1][dt] = __builtin_amdgcn_mfma_f32_16x16x32_bf16(pa1, vf, o_[1][dt], 0, 0, 0);
            }
        }

        __syncthreads();
    }

    #pragma unroll
    for (int tq = 0; tq < 2; ++tq) {
        #pragma unroll
        for (int j = 0; j < 4; ++j) {
            float inv = 1.0f / l_[tq][j];
            size_t rb = (size_t)(b * S + qbase + tq * 16 + 4 * g + j) * 2048 + h * HD;
            #pragma unroll
            for (int dt = 0; dt < 8; ++dt)
                O[rb + dt * 16 + cc] = f2bs(o_[tq][dt][j] * inv);
        }
    }
}

}  // namespace

extern "C" void kernel_launch(void* const* d_in, const int* in_sizes, int n_in,
                              void* d_out, int out_size, void* d_ws, size_t ws_size,
                              hipStream_t stream) {
    const float* hs = (const float*)d_in[0];
    const float* Wq = (const float*)d_in[1];
    const float* Wk = (const float*)d_in[2];
    const float* Wv = (const float*)d_in[3];
    const float* Wo = (const float*)d_in[4];
    float* out = (float*)d_out;

    // Workspace: hsb[M*2048] (reused as AOb) | WqkvT[3072*2048] | WoT[2048*2048] |
    // QKVf[M*3072] | VT[8*128*2048]   -> ~85 MB
    char* p = (char*)d_ws;
    s16* hsb   = (s16*)p;  p += (size_t)M * 2048 * 2;
    s16* WqkvT = (s16*)p;  p += (size_t)QKVN * 2048 * 2;
    s16* WoT   = (s16*)p;  p += (size_t)2048 * 2048 * 2;
    s16* QKVf  = (s16*)p;  p += (size_t)M * QKVN * 2;
    s16* VT    = (s16*)p;
    s16* AOb   = hsb;   // reuse after fused projection consumed hsb

    dim3 blk(256);
    const float qscale = 0.08838834764831845f;  // 1/sqrt(128)

    cast_kernel<<<(M * H / 8 + 255) / 256, blk, 0, stream>>>(hs, hsb, M * H / 8);
    // WqkvT rows: [0,2048) = Wq^T, [2048,2560) = Wk^T, [2560,3072) = Wv^T
    transpose_cast<<<dim3(2048 / 64, 2048 / 64), blk, 0, stream>>>(Wq, WqkvT, 2048, 2048);
    transpose_cast<<<dim3(512 / 64, 2048 / 64), blk, 0, stream>>>(Wk, WqkvT + (size_t)2048 * 2048, 2048, 512);
    transpose_cast<<<dim3(512 / 64, 2048 / 64), blk, 0, stream>>>(Wv, WqkvT + (size_t)2560 * 2048, 2048, 512);
    transpose_cast<<<dim3(2048 / 64, 2048 / 64), blk, 0, stream>>>(Wo, WoT, 2048, 2048);

    // Fused QKV projection: [M,3072] = hsb @ WqkvT^T  (768 blocks, 3/CU)
    gemm_bf16<true><<<dim3(QKVN / 128, M / 128), blk, 0, stream>>>(hsb, WqkvT, QKVf, QKVN, 2048);

    // RoPE: Q (scale folded; 16 heads at stride 3072), K (4 heads at col 2048)
    rope_kernel<<<(M * NH * 8) / 256, blk, 0, stream>>>(QKVf, 15, 7, QKVN, qscale, M * NH * 8);
    rope_kernel<<<(M * NKV * 8) / 256, blk, 0, stream>>>(QKVf + 2048, 3, 5, QKVN, 1.0f, M * NKV * 8);

    // V transpose from QKV col 2560
    vtrans<<<dim3(S / 64, B * NKV * 2), blk, 0, stream>>>(QKVf + 2560, VT);

    // Attention (R11 structure; Q stride 3072, K at QKVf+2048)
    attn_mfma<<<B * NKV * (S / 32), blk, 0, stream>>>(QKVf, QKVf + 2048, VT, AOb);

    // Output projection
    gemm_bf16<false><<<dim3(2048 / 128, M / 128), blk, 0, stream>>>(AOb, WoT, out, 2048, 2048);
}